// Round 2
// baseline (2564.878 us; speedup 1.0000x reference)
//
#include <hip/hip_runtime.h>
#include <math.h>

#define NN 50000
#define EE 800000
#define HH 4
#define DD 128
#define HDIM 512
#define LL 4

__device__ __forceinline__ float lk(float x, float s){ return x > 0.f ? x : s*x; }
// bf16 helpers (round-to-nearest-even pack, shift unpack)
__device__ __forceinline__ unsigned short f2bf(float f){
  unsigned u = __float_as_uint(f);
  u += 0x7FFFu + ((u >> 16) & 1u);
  return (unsigned short)(u >> 16);
}
__device__ __forceinline__ float lo16(unsigned u){ return __uint_as_float(u << 16); }
__device__ __forceinline__ float hi16(unsigned u){ return __uint_as_float(u & 0xFFFF0000u); }
__device__ __forceinline__ float bf2f(unsigned short u){ return __uint_as_float(((unsigned)u) << 16); }

// ---------------- CSR build (dst-sorted edge list; no scatter atomics in hot path) -------------
__global__ void k_zero(int* p, int n){ int i = blockIdx.x*blockDim.x+threadIdx.x; if(i<n) p[i]=0; }

__global__ void k_hist(const int* __restrict__ dst, int* __restrict__ cnt){
  int e = blockIdx.x*blockDim.x+threadIdx.x;
  if (e < EE) atomicAdd(&cnt[dst[e]], 1);
}

__global__ __launch_bounds__(1024) void k_scan(const int* __restrict__ cnt, int* __restrict__ row_ptr){
  __shared__ int part[1024];
  int t = threadIdx.x;
  const int chunk = (NN + 1023)/1024;           // 49
  int b = t*chunk, e = b+chunk;
  if (b > NN) b = NN;
  if (e > NN) e = NN;
  int s = 0;
  for (int i=b;i<e;++i) s += cnt[i];
  part[t] = s;
  __syncthreads();
  for (int off=1; off<1024; off<<=1){
    int v = (t>=off) ? part[t-off] : 0;
    __syncthreads();
    part[t] += v;
    __syncthreads();
  }
  int run = part[t] - s;
  for (int i=b;i<e;++i){ row_ptr[i] = run; run += cnt[i]; }
  if (t==1023) row_ptr[NN] = part[1023];
}

__global__ void k_copy(const int* __restrict__ a, int* __restrict__ b, int n){
  int i = blockIdx.x*blockDim.x+threadIdx.x; if(i<n) b[i]=a[i];
}

__global__ void k_fill(const int* __restrict__ src, const int* __restrict__ dst,
                       int* __restrict__ cursor, int* __restrict__ csr_src){
  int e = blockIdx.x*blockDim.x+threadIdx.x;
  if (e >= EE) return;
  int d = dst[e];
  int p = atomicAdd(&cursor[d], 1);
  csr_src[p] = src[e];
}

// ---------------- attention premix: A[k,h] = sum_d Wf[k,h*128+d]*al[h,d] (el = x @ A) ----------
__global__ void k_premix(const float* __restrict__ Wf, const float* __restrict__ al,
                         const float* __restrict__ ar, float* __restrict__ AB){
  int t = blockIdx.x*blockDim.x + threadIdx.x;
  if (t >= 1024) return;
  int which = t >> 9;
  int idx = t & 511;
  int k = idx >> 2, h = idx & 3;
  const float* av = which ? ar : al;
  const float* wrow = Wf + k*HDIM + h*DD;
  const float* arow = av + h*DD;
  float s = 0.f;
  for (int d=0; d<DD; ++d) s += wrow[d]*arow[d];
  AB[k*8 + which*4 + h] = s;
}

// ---------------- el/er mini-GEMM: [N,128] @ [128,8] -------------------------------------------
__global__ void k_attn(const float* __restrict__ x, const float* __restrict__ AB,
                       float* __restrict__ el, float* __restrict__ er){
  int t = threadIdx.x;
  int n = blockIdx.x*32 + (t>>3);
  int c = t & 7;
  if (n >= NN) return;
  const float* xr = x + (size_t)n*DD;
  float acc = 0.f;
  for (int k=0;k<DD;++k) acc += xr[k]*AB[k*8+c];
  if (c < 4) el[n*4+c] = acc; else er[n*4 + (c-4)] = acc;
}

// ---------------- GEMM1: feat(bf16)[N,512] = x@Wf ; res(bf16)[N,512] = x@Wr --------------------
// thread t owns cols {2t, 2t+1}
__global__ __launch_bounds__(256) void k_gemm1(const float* __restrict__ x,
                                               const float* __restrict__ Wf,
                                               const float* __restrict__ Wr,
                                               unsigned short* __restrict__ featH,
                                               unsigned short* __restrict__ hbuf){
  __shared__ float sx[16*128];
  int t = threadIdx.x;
  int row0 = blockIdx.x*16;                      // NN % 16 == 0
  #pragma unroll
  for (int j=0;j<8;++j){
    int idx = t + j*256;
    sx[idx] = x[(size_t)row0*128 + idx];
  }
  __syncthreads();
  float4 acc[16];                                // .x,.y = feat cols 2t,2t+1 ; .z,.w = res cols
  #pragma unroll
  for (int r=0;r<16;++r) acc[r] = make_float4(0.f,0.f,0.f,0.f);
  for (int kk=0; kk<128; kk+=4){
    float2 wf[4], wr[4];
    #pragma unroll
    for (int kq=0;kq<4;++kq){
      wf[kq] = *(const float2*)&Wf[(size_t)(kk+kq)*HDIM + 2*t];
      wr[kq] = *(const float2*)&Wr[(size_t)(kk+kq)*HDIM + 2*t];
    }
    #pragma unroll
    for (int r=0;r<16;++r){
      float4 xv = *(const float4*)&sx[r*128+kk];
      acc[r].x += xv.x*wf[0].x + xv.y*wf[1].x + xv.z*wf[2].x + xv.w*wf[3].x;
      acc[r].y += xv.x*wf[0].y + xv.y*wf[1].y + xv.z*wf[2].y + xv.w*wf[3].y;
      acc[r].z += xv.x*wr[0].x + xv.y*wr[1].x + xv.z*wr[2].x + xv.w*wr[3].x;
      acc[r].w += xv.x*wr[0].y + xv.y*wr[1].y + xv.z*wr[2].y + xv.w*wr[3].y;
    }
  }
  #pragma unroll
  for (int r=0;r<16;++r){
    size_t rb = (size_t)(row0+r)*HDIM + 2*t;
    ushort2 pf; pf.x = f2bf(acc[r].x); pf.y = f2bf(acc[r].y);
    ushort2 pr; pr.x = f2bf(acc[r].z); pr.y = f2bf(acc[r].w);
    *(ushort2*)(featH + rb) = pf;
    *(ushort2*)(hbuf + rb)  = pr;
  }
}

// ---------------- edge softmax + aggregation; h overwrites res in hbuf (same rows only) --------
__global__ __launch_bounds__(256) void k_agg(const unsigned short* __restrict__ featH,
                                             unsigned short* __restrict__ hbuf,
                                             const float* __restrict__ el,
                                             const float* __restrict__ er,
                                             const int* __restrict__ row_ptr,
                                             const int* __restrict__ csr_src,
                                             const float* __restrict__ b_gat){
  int t = threadIdx.x;
  int lane = t & 63;
  int node = blockIdx.x*4 + (t>>6);              // NN % 4 == 0, grid exact
  int beg = row_ptr[node], end = row_ptr[node+1];
  float4 erv = *(const float4*)&er[(size_t)node*4];

  // pass 1: online softmax stats per head
  float m[4] = {-1e30f,-1e30f,-1e30f,-1e30f};
  float z[4] = {0.f,0.f,0.f,0.f};
  for (int i = beg + lane; i < end; i += 64){
    int s = csr_src[i];
    float4 ev = *(const float4*)&el[(size_t)s*4];
    float e4[4] = { lk(ev.x+erv.x,0.2f), lk(ev.y+erv.y,0.2f),
                    lk(ev.z+erv.z,0.2f), lk(ev.w+erv.w,0.2f) };
    #pragma unroll
    for (int hh=0; hh<4; ++hh){
      float e = e4[hh];
      if (e > m[hh]) { z[hh] = z[hh]*__expf(m[hh]-e) + 1.f; m[hh] = e; }
      else           { z[hh] += __expf(e - m[hh]); }
    }
  }
  #pragma unroll
  for (int off=32; off>0; off>>=1){
    #pragma unroll
    for (int hh=0; hh<4; ++hh){
      float mo = __shfl_xor(m[hh], off);
      float zo = __shfl_xor(z[hh], off);
      float mn = fmaxf(m[hh], mo);
      z[hh] = z[hh]*__expf(m[hh]-mn) + zo*__expf(mo-mn);
      m[hh] = mn;
    }
  }
  float iz[4];
  #pragma unroll
  for (int hh=0; hh<4; ++hh) iz[hh] = 1.f / fmaxf(z[hh], 1e-20f);

  // pass 2: lane owns channels [4*lane..4*lane+3] and [256+4*lane..+3]
  int hsel = lane >> 5;
  float m1 = hsel ? m[1] : m[0],  m2 = hsel ? m[3] : m[2];
  float z1 = hsel ? iz[1] : iz[0], z2 = hsel ? iz[3] : iz[2];
  float er1 = hsel ? erv.y : erv.x, er2 = hsel ? erv.w : erv.z;
  float acc[8] = {0.f,0.f,0.f,0.f,0.f,0.f,0.f,0.f};
  for (int i = beg; i < end; ++i){
    int s = csr_src[i];
    float4 ev = *(const float4*)&el[(size_t)s*4];
    float e1 = lk((hsel ? ev.y : ev.x) + er1, 0.2f);
    float e2 = lk((hsel ? ev.w : ev.z) + er2, 0.2f);
    float w1 = __expf(e1 - m1) * z1;
    float w2 = __expf(e2 - m2) * z2;
    const uint2* fp = (const uint2*)(featH + (size_t)s*HDIM);
    uint2 fa = fp[lane];
    uint2 fb = fp[64 + lane];
    acc[0] += w1*lo16(fa.x); acc[1] += w1*hi16(fa.x);
    acc[2] += w1*lo16(fa.y); acc[3] += w1*hi16(fa.y);
    acc[4] += w2*lo16(fb.x); acc[5] += w2*hi16(fb.x);
    acc[6] += w2*lo16(fb.y); acc[7] += w2*hi16(fb.y);
  }

  // epilogue: + residual + bias, leaky(0.01); overwrite res with h (bf16)
  uint2* rp = (uint2*)(hbuf + (size_t)node*HDIM);
  uint2 r1 = rp[lane], r2 = rp[64+lane];
  const float4* bp = (const float4*)b_gat;
  float4 b1 = bp[lane], b2 = bp[64+lane];
  float o0 = lk(acc[0]+lo16(r1.x)+b1.x, 0.01f);
  float o1 = lk(acc[1]+hi16(r1.x)+b1.y, 0.01f);
  float o2 = lk(acc[2]+lo16(r1.y)+b1.z, 0.01f);
  float o3 = lk(acc[3]+hi16(r1.y)+b1.w, 0.01f);
  float o4 = lk(acc[4]+lo16(r2.x)+b2.x, 0.01f);
  float o5 = lk(acc[5]+hi16(r2.x)+b2.y, 0.01f);
  float o6 = lk(acc[6]+lo16(r2.y)+b2.z, 0.01f);
  float o7 = lk(acc[7]+hi16(r2.y)+b2.w, 0.01f);
  uint2 w1v, w2v;
  w1v.x = (unsigned)f2bf(o0) | ((unsigned)f2bf(o1) << 16);
  w1v.y = (unsigned)f2bf(o2) | ((unsigned)f2bf(o3) << 16);
  w2v.x = (unsigned)f2bf(o4) | ((unsigned)f2bf(o5) << 16);
  w2v.y = (unsigned)f2bf(o6) | ((unsigned)f2bf(o7) << 16);
  rp[lane] = w1v; rp[64+lane] = w2v;
}

// ---------------- GEMM3 + LayerNorm fused: out[N,128] = LN(h@Wn + bn)*g + b --------------------
__global__ __launch_bounds__(256) void k_gemm3ln(const unsigned short* __restrict__ h,
                                                 const float* __restrict__ Wn,
                                                 const float* __restrict__ bn,
                                                 const float* __restrict__ lng,
                                                 const float* __restrict__ lnb,
                                                 float* __restrict__ out){
  __shared__ float sh[32*128];
  int t = threadIdx.x;
  int col = t & 127, rh = t >> 7;
  int row0 = blockIdx.x*32;
  float acc[16];
  #pragma unroll
  for (int r=0;r<16;++r) acc[r]=0.f;
  for (int kb=0; kb<4; ++kb){
    __syncthreads();
    #pragma unroll
    for (int j=0;j<16;++j){
      int idx = t + j*256;
      int r = idx >> 7, k = idx & 127;
      int grow = row0 + r;
      sh[idx] = (grow < NN) ? bf2f(h[(size_t)grow*HDIM + kb*128 + k]) : 0.f;
    }
    __syncthreads();
    for (int kk=0; kk<128; kk+=4){
      float w0 = Wn[(size_t)(kb*128+kk+0)*128 + col];
      float w1 = Wn[(size_t)(kb*128+kk+1)*128 + col];
      float w2 = Wn[(size_t)(kb*128+kk+2)*128 + col];
      float w3 = Wn[(size_t)(kb*128+kk+3)*128 + col];
      #pragma unroll
      for (int r=0;r<16;++r){
        float4 xv = *(const float4*)&sh[(rh*16+r)*128 + kk];
        acc[r] += xv.x*w0 + xv.y*w1 + xv.z*w2 + xv.w*w3;
      }
    }
  }
  // y into LDS, then LN (4 waves x 8 rows)
  float bnv = bn[col];
  __syncthreads();
  #pragma unroll
  for (int r=0;r<16;++r) sh[(rh*16+r)*128 + col] = acc[r] + bnv;
  __syncthreads();
  int lane = t & 63, w = t >> 6;
  float g0 = lng[lane], g1 = lng[64+lane];
  float bb0 = lnb[lane], bb1 = lnb[64+lane];
  for (int lr = w*8; lr < w*8+8; ++lr){
    float v0 = sh[lr*128 + lane], v1 = sh[lr*128 + 64 + lane];
    float s = v0 + v1;
    #pragma unroll
    for (int off=32; off>0; off>>=1) s += __shfl_xor(s, off);
    float mu = s * (1.f/128.f);
    float d0 = v0-mu, d1 = v1-mu;
    float q = d0*d0 + d1*d1;
    #pragma unroll
    for (int off=32; off>0; off>>=1) q += __shfl_xor(q, off);
    float inv = rsqrtf(q*(1.f/128.f) + 1e-5f);
    int grow = row0 + lr;
    if (grow < NN){
      out[(size_t)grow*128 + lane]      = d0*inv*g0 + bb0;
      out[(size_t)grow*128 + 64 + lane] = d1*inv*g1 + bb1;
    }
  }
}

extern "C" void kernel_launch(void* const* d_in, const int* in_sizes, int n_in,
                              void* d_out, int out_size, void* d_ws, size_t ws_size,
                              hipStream_t stream){
  const float* features = (const float*)d_in[0];
  const int*   src      = (const int*)d_in[1];
  const int*   dst      = (const int*)d_in[2];
  const float* W_fc     = (const float*)d_in[3];
  const float* attn_l   = (const float*)d_in[4];
  const float* attn_r   = (const float*)d_in[5];
  const float* W_res    = (const float*)d_in[6];
  const float* b_gat    = (const float*)d_in[7];
  const float* W_nrm    = (const float*)d_in[8];
  const float* b_nrm    = (const float*)d_in[9];
  const float* ln_g     = (const float*)d_in[10];
  const float* ln_b     = (const float*)d_in[11];
  float* out = (float*)d_out;

  // workspace layout (~133 MB total)
  float* xA = (float*)d_ws;                                  // [N,128] fp32   25.6 MB
  float* el = xA + (size_t)NN*DD;                            // [N,4]           0.8 MB
  float* er = el + (size_t)NN*4;                             // [N,4]           0.8 MB
  float* AB = er + (size_t)NN*4;                             // [128,8]         4 KB
  unsigned short* featH = (unsigned short*)(AB + 1024);      // [N,512] bf16   51.2 MB
  unsigned short* hbuf  = featH + (size_t)NN*HDIM;           // [N,512] bf16   51.2 MB
  int* row_ptr = (int*)(hbuf + (size_t)NN*HDIM);             // N+1
  int* cursor  = row_ptr + (NN+1);                           // N
  int* csr_src = cursor + NN;                                // E               3.2 MB

  // CSR build
  k_zero<<<(NN+255)/256, 256, 0, stream>>>(cursor, NN);
  k_hist<<<(EE+255)/256, 256, 0, stream>>>(dst, cursor);
  k_scan<<<1, 1024, 0, stream>>>(cursor, row_ptr);
  k_copy<<<(NN+255)/256, 256, 0, stream>>>(row_ptr, cursor, NN);
  k_fill<<<(EE+255)/256, 256, 0, stream>>>(src, dst, cursor, csr_src);

  const float* x = features;
  for (int l=0; l<LL; ++l){
    const float* Wf = W_fc  + (size_t)l*DD*HDIM;
    const float* Wr = W_res + (size_t)l*DD*HDIM;
    const float* al = attn_l + (size_t)l*HH*DD;
    const float* ar = attn_r + (size_t)l*HH*DD;
    const float* bg = b_gat  + (size_t)l*HDIM;
    const float* Wn = W_nrm  + (size_t)l*HDIM*DD;
    const float* bn = b_nrm  + (size_t)l*DD;
    const float* lg = ln_g   + (size_t)l*DD;
    const float* lb = ln_b   + (size_t)l*DD;
    float* xo = ((l & 1) == 0) ? xA : out;   // xA, out, xA, out — final lands in d_out

    k_premix<<<1, 1024, 0, stream>>>(Wf, al, ar, AB);
    k_attn<<<(NN+31)/32, 256, 0, stream>>>(x, AB, el, er);
    k_gemm1<<<NN/16, 256, 0, stream>>>(x, Wf, Wr, featH, hbuf);
    k_agg<<<NN/4, 256, 0, stream>>>(featH, hbuf, el, er, row_ptr, csr_src, bg);
    k_gemm3ln<<<(NN+31)/32, 256, 0, stream>>>(hbuf, Wn, bn, lg, lb, xo);
    x = xo;
  }
}

// Round 3
// 1147.916 us; speedup vs baseline: 2.2344x; 2.2344x over previous
//
#include <hip/hip_runtime.h>
#include <math.h>

#define NN 50000
#define NPAD 50048            // 391 * 128
#define EE 800000
#define HH 4
#define DD 128
#define HDIM 512
#define LL 4

typedef __attribute__((ext_vector_type(8))) short short8;
typedef __attribute__((ext_vector_type(4))) float f32x4;

__device__ __forceinline__ float lk(float x, float s){ return x > 0.f ? x : s*x; }
__device__ __forceinline__ unsigned short f2bf(float f){
  unsigned u = __float_as_uint(f);
  u += 0x7FFFu + ((u >> 16) & 1u);
  return (unsigned short)(u >> 16);
}
__device__ __forceinline__ float lo16(unsigned u){ return __uint_as_float(u << 16); }
__device__ __forceinline__ float hi16(unsigned u){ return __uint_as_float(u & 0xFFFF0000u); }

// ---------------- CSR build ---------------------------------------------------------------------
__global__ void k_zero(int* p, int n){ int i = blockIdx.x*blockDim.x+threadIdx.x; if(i<n) p[i]=0; }

__global__ void k_hist(const int* __restrict__ dst, int* __restrict__ cnt){
  int e = blockIdx.x*blockDim.x+threadIdx.x;
  if (e < EE) atomicAdd(&cnt[dst[e]], 1);
}

__global__ __launch_bounds__(1024) void k_scan(const int* __restrict__ cnt, int* __restrict__ row_ptr){
  __shared__ int part[1024];
  int t = threadIdx.x;
  const int chunk = (NN + 1023)/1024;
  int b = t*chunk, e = b+chunk;
  if (b > NN) b = NN;
  if (e > NN) e = NN;
  int s = 0;
  for (int i=b;i<e;++i) s += cnt[i];
  part[t] = s;
  __syncthreads();
  for (int off=1; off<1024; off<<=1){
    int v = (t>=off) ? part[t-off] : 0;
    __syncthreads();
    part[t] += v;
    __syncthreads();
  }
  int run = part[t] - s;
  for (int i=b;i<e;++i){ row_ptr[i] = run; run += cnt[i]; }
  if (t==1023) row_ptr[NN] = part[1023];
}

__global__ void k_copy(const int* __restrict__ a, int* __restrict__ b, int n){
  int i = blockIdx.x*blockDim.x+threadIdx.x; if(i<n) b[i]=a[i];
}

__global__ void k_fill(const int* __restrict__ src, const int* __restrict__ dst,
                       int* __restrict__ cursor, int* __restrict__ csr_src){
  int e = blockIdx.x*blockDim.x+threadIdx.x;
  if (e >= EE) return;
  int d = dst[e];
  int p = atomicAdd(&cursor[d], 1);
  csr_src[p] = src[e];
}

// ---------------- weight conversion (bf16, transposed for MFMA B-operand) ----------------------
// W2t[l][n][k] = (n<512 ? W_fc[l][k][n] : W_res[l][k][n-512])
__global__ void k_cvtw2(const float* __restrict__ Wf, const float* __restrict__ Wr,
                        unsigned short* __restrict__ W2t){
  int idx = blockIdx.x*blockDim.x + threadIdx.x;     // < 4*1024*128
  int l = idx >> 17, rem = idx & 131071;
  int n = rem >> 7, k = rem & 127;
  float v = (n < 512) ? Wf[(size_t)(l*128 + k)*512 + n]
                      : Wr[(size_t)(l*128 + k)*512 + (n-512)];
  W2t[idx] = f2bf(v);
}
// Wnt[l][n][k] = W_nrm[l][k][n]
__global__ void k_cvtwn(const float* __restrict__ Wn, unsigned short* __restrict__ Wnt){
  int idx = blockIdx.x*blockDim.x + threadIdx.x;     // < 4*128*512
  int l = idx >> 16, rem = idx & 65535;
  int n = rem >> 9, k = rem & 511;
  Wnt[idx] = f2bf(Wn[(size_t)(l*512 + k)*128 + n]);
}
// xb[NPAD,128] bf16 from features (pad rows = 0)
__global__ void k_cvtx(const float* __restrict__ x, unsigned short* __restrict__ xb){
  int idx = blockIdx.x*blockDim.x + threadIdx.x;     // < NPAD*128
  int row = idx >> 7;
  xb[idx] = (row < NN) ? f2bf(x[idx]) : (unsigned short)0;
}

// ---------------- GEMM1 (MFMA): [NPAD,128]bf16 @ W2t-block[128cols,128k] -> bf16 out -----------
__global__ __launch_bounds__(256) void k_gemm1m(const unsigned short* __restrict__ xb,
                                                const unsigned short* __restrict__ W2t,
                                                unsigned short* __restrict__ featH,
                                                unsigned short* __restrict__ hbuf){
  __shared__ __attribute__((aligned(16))) char smem[2*128*136*2];
  unsigned short* sA = (unsigned short*)smem;
  unsigned short* sB = sA + 128*136;
  int t = threadIdx.x;
  int m0 = blockIdx.x*128;
  int n0 = blockIdx.y*128;
  #pragma unroll
  for (int j=0;j<8;++j){
    int c = t + j*256; int r = c>>4, kc = c&15;
    uint4 v = *(const uint4*)(xb + (size_t)(m0+r)*128 + kc*8);
    *(uint4*)(sA + r*136 + kc*8) = v;
  }
  #pragma unroll
  for (int j=0;j<8;++j){
    int c = t + j*256; int r = c>>4, kc = c&15;
    uint4 v = *(const uint4*)(W2t + (size_t)(n0+r)*128 + kc*8);
    *(uint4*)(sB + r*136 + kc*8) = v;
  }
  __syncthreads();

  int lane = t & 63, w = t >> 6;
  int wm = (w & 1)*64, wn = (w >> 1)*64;
  int lrow = lane & 15, quad = lane >> 4;
  f32x4 acc[4][4];
  #pragma unroll
  for (int mt=0;mt<4;++mt)
    #pragma unroll
    for (int nt=0;nt<4;++nt) acc[mt][nt] = (f32x4){0.f,0.f,0.f,0.f};

  #pragma unroll
  for (int kq=0;kq<4;++kq){
    int kb = kq*32 + quad*8;
    short8 af[4], bf[4];
    #pragma unroll
    for (int mt=0;mt<4;++mt) af[mt] = *(const short8*)(sA + (wm+mt*16+lrow)*136 + kb);
    #pragma unroll
    for (int nt=0;nt<4;++nt) bf[nt] = *(const short8*)(sB + (wn+nt*16+lrow)*136 + kb);
    #pragma unroll
    for (int mt=0;mt<4;++mt)
      #pragma unroll
      for (int nt=0;nt<4;++nt)
        acc[mt][nt] = __builtin_amdgcn_mfma_f32_16x16x32_bf16(af[mt], bf[nt], acc[mt][nt], 0,0,0);
  }

  // repack bf16 through LDS for coalesced stores
  __syncthreads();
  #pragma unroll
  for (int mt=0;mt<4;++mt)
    #pragma unroll
    for (int nt=0;nt<4;++nt)
      #pragma unroll
      for (int r=0;r<4;++r)
        sA[(wm+mt*16+quad*4+r)*136 + wn+nt*16+lrow] = f2bf(acc[mt][nt][r]);
  __syncthreads();
  unsigned short* dstB = (n0 < 512) ? (featH + (size_t)m0*512 + n0)
                                    : (hbuf  + (size_t)m0*512 + (n0-512));
  #pragma unroll
  for (int j=0;j<8;++j){
    int c = t + j*256; int r = c>>4, kc = c&15;
    uint4 v = *(const uint4*)(sA + r*136 + kc*8);
    *(uint4*)(dstB + (size_t)r*512 + kc*8) = v;
  }
}

// ---------------- el/er from featH: one wave per node ------------------------------------------
__global__ __launch_bounds__(256) void k_attn2(const unsigned short* __restrict__ featH,
                                               const float* __restrict__ al,
                                               const float* __restrict__ ar,
                                               float* __restrict__ el, float* __restrict__ er){
  int t = threadIdx.x, lane = t & 63, w = t >> 6;
  int node = blockIdx.x*4 + w;                  // grid exact: NN/4
  const uint2* fp = (const uint2*)(featH + (size_t)node*HDIM);
  uint2 fa = fp[lane];                          // cols 4*lane..+3   (head lane>>5)
  uint2 fb = fp[64+lane];                       // cols 256+4*lane   (head 2+(lane>>5))
  float4 a1 = *(const float4*)(al + 4*lane);
  float4 a2 = *(const float4*)(al + 256 + 4*lane);
  float4 r1 = *(const float4*)(ar + 4*lane);
  float4 r2 = *(const float4*)(ar + 256 + 4*lane);
  float f0 = lo16(fa.x), f1 = hi16(fa.x), f2 = lo16(fa.y), f3 = hi16(fa.y);
  float g0 = lo16(fb.x), g1 = hi16(fb.x), g2 = lo16(fb.y), g3 = hi16(fb.y);
  float pel1 = f0*a1.x + f1*a1.y + f2*a1.z + f3*a1.w;
  float pel2 = g0*a2.x + g1*a2.y + g2*a2.z + g3*a2.w;
  float per1 = f0*r1.x + f1*r1.y + f2*r1.z + f3*r1.w;
  float per2 = g0*r2.x + g1*r2.y + g2*r2.z + g3*r2.w;
  #pragma unroll
  for (int off=16; off>0; off>>=1){
    pel1 += __shfl_xor(pel1, off);
    pel2 += __shfl_xor(pel2, off);
    per1 += __shfl_xor(per1, off);
    per2 += __shfl_xor(per2, off);
  }
  if ((lane & 31) == 0){
    int h = lane >> 5;
    el[node*4 + h]     = pel1;
    er[node*4 + h]     = per1;
    el[node*4 + 2 + h] = pel2;
    er[node*4 + 2 + h] = per2;
  }
}

// ---------------- edge softmax + aggregation; h overwrites res in hbuf -------------------------
__global__ __launch_bounds__(256) void k_agg(const unsigned short* __restrict__ featH,
                                             unsigned short* __restrict__ hbuf,
                                             const float* __restrict__ el,
                                             const float* __restrict__ er,
                                             const int* __restrict__ row_ptr,
                                             const int* __restrict__ csr_src,
                                             const float* __restrict__ b_gat){
  int t = threadIdx.x;
  int lane = t & 63;
  int node = blockIdx.x*4 + (t>>6);
  int beg = row_ptr[node], end = row_ptr[node+1];
  float4 erv = *(const float4*)&er[(size_t)node*4];

  float m[4] = {-1e30f,-1e30f,-1e30f,-1e30f};
  float z[4] = {0.f,0.f,0.f,0.f};
  for (int i = beg + lane; i < end; i += 64){
    int s = csr_src[i];
    float4 ev = *(const float4*)&el[(size_t)s*4];
    float e4[4] = { lk(ev.x+erv.x,0.2f), lk(ev.y+erv.y,0.2f),
                    lk(ev.z+erv.z,0.2f), lk(ev.w+erv.w,0.2f) };
    #pragma unroll
    for (int hh=0; hh<4; ++hh){
      float e = e4[hh];
      if (e > m[hh]) { z[hh] = z[hh]*__expf(m[hh]-e) + 1.f; m[hh] = e; }
      else           { z[hh] += __expf(e - m[hh]); }
    }
  }
  #pragma unroll
  for (int off=32; off>0; off>>=1){
    #pragma unroll
    for (int hh=0; hh<4; ++hh){
      float mo = __shfl_xor(m[hh], off);
      float zo = __shfl_xor(z[hh], off);
      float mn = fmaxf(m[hh], mo);
      z[hh] = z[hh]*__expf(m[hh]-mn) + zo*__expf(mo-mn);
      m[hh] = mn;
    }
  }
  float iz[4];
  #pragma unroll
  for (int hh=0; hh<4; ++hh) iz[hh] = 1.f / fmaxf(z[hh], 1e-20f);

  int hsel = lane >> 5;
  float m1 = hsel ? m[1] : m[0],  m2 = hsel ? m[3] : m[2];
  float z1 = hsel ? iz[1] : iz[0], z2 = hsel ? iz[3] : iz[2];
  float er1 = hsel ? erv.y : erv.x, er2 = hsel ? erv.w : erv.z;
  float acc[8] = {0.f,0.f,0.f,0.f,0.f,0.f,0.f,0.f};
  for (int i = beg; i < end; ++i){
    int s = csr_src[i];
    float4 ev = *(const float4*)&el[(size_t)s*4];
    float e1 = lk((hsel ? ev.y : ev.x) + er1, 0.2f);
    float e2 = lk((hsel ? ev.w : ev.z) + er2, 0.2f);
    float w1 = __expf(e1 - m1) * z1;
    float w2 = __expf(e2 - m2) * z2;
    const uint2* fp = (const uint2*)(featH + (size_t)s*HDIM);
    uint2 fa = fp[lane];
    uint2 fb = fp[64 + lane];
    acc[0] += w1*lo16(fa.x); acc[1] += w1*hi16(fa.x);
    acc[2] += w1*lo16(fa.y); acc[3] += w1*hi16(fa.y);
    acc[4] += w2*lo16(fb.x); acc[5] += w2*hi16(fb.x);
    acc[6] += w2*lo16(fb.y); acc[7] += w2*hi16(fb.y);
  }

  uint2* rp = (uint2*)(hbuf + (size_t)node*HDIM);
  uint2 r1 = rp[lane], r2 = rp[64+lane];
  const float4* bp = (const float4*)b_gat;
  float4 b1 = bp[lane], b2 = bp[64+lane];
  float o0 = lk(acc[0]+lo16(r1.x)+b1.x, 0.01f);
  float o1 = lk(acc[1]+hi16(r1.x)+b1.y, 0.01f);
  float o2 = lk(acc[2]+lo16(r1.y)+b1.z, 0.01f);
  float o3 = lk(acc[3]+hi16(r1.y)+b1.w, 0.01f);
  float o4 = lk(acc[4]+lo16(r2.x)+b2.x, 0.01f);
  float o5 = lk(acc[5]+hi16(r2.x)+b2.y, 0.01f);
  float o6 = lk(acc[6]+lo16(r2.y)+b2.z, 0.01f);
  float o7 = lk(acc[7]+hi16(r2.y)+b2.w, 0.01f);
  uint2 w1v, w2v;
  w1v.x = (unsigned)f2bf(o0) | ((unsigned)f2bf(o1) << 16);
  w1v.y = (unsigned)f2bf(o2) | ((unsigned)f2bf(o3) << 16);
  w2v.x = (unsigned)f2bf(o4) | ((unsigned)f2bf(o5) << 16);
  w2v.y = (unsigned)f2bf(o6) | ((unsigned)f2bf(o7) << 16);
  rp[lane] = w1v; rp[64+lane] = w2v;
}

// ---------------- GEMM3 (MFMA, K=512) + LayerNorm; writes bf16 xb and optional fp32 out --------
__global__ __launch_bounds__(256) void k_gemm3m(const unsigned short* __restrict__ h,
                                                const unsigned short* __restrict__ Wnt,
                                                const float* __restrict__ bn,
                                                const float* __restrict__ lng,
                                                const float* __restrict__ lnb,
                                                float* __restrict__ out,
                                                unsigned short* __restrict__ xb,
                                                int writeOut){
  __shared__ __attribute__((aligned(16))) char smem[2*128*136*2];
  unsigned short* sA = (unsigned short*)smem;
  unsigned short* sB = sA + 128*136;
  float* yf = (float*)smem;                     // 128*132*4 = 67584 <= 69632
  int t = threadIdx.x;
  int m0 = blockIdx.x*128;
  int lane = t & 63, w = t >> 6;
  int wm = (w & 1)*64, wn = (w >> 1)*64;
  int lrow = lane & 15, quad = lane >> 4;

  f32x4 acc[4][4];
  #pragma unroll
  for (int mt=0;mt<4;++mt)
    #pragma unroll
    for (int nt=0;nt<4;++nt) acc[mt][nt] = (f32x4){0.f,0.f,0.f,0.f};

  for (int kc2=0; kc2<4; ++kc2){                // K chunks of 128
    if (kc2) __syncthreads();
    #pragma unroll
    for (int j=0;j<8;++j){
      int c = t + j*256; int r = c>>4, kc = c&15;
      uint4 v = *(const uint4*)(h + (size_t)(m0+r)*512 + kc2*128 + kc*8);
      *(uint4*)(sA + r*136 + kc*8) = v;
    }
    #pragma unroll
    for (int j=0;j<8;++j){
      int c = t + j*256; int r = c>>4, kc = c&15;
      uint4 v = *(const uint4*)(Wnt + (size_t)r*512 + kc2*128 + kc*8);
      *(uint4*)(sB + r*136 + kc*8) = v;
    }
    __syncthreads();
    #pragma unroll
    for (int kq=0;kq<4;++kq){
      int kb = kq*32 + quad*8;
      short8 af[4], bf[4];
      #pragma unroll
      for (int mt=0;mt<4;++mt) af[mt] = *(const short8*)(sA + (wm+mt*16+lrow)*136 + kb);
      #pragma unroll
      for (int nt=0;nt<4;++nt) bf[nt] = *(const short8*)(sB + (wn+nt*16+lrow)*136 + kb);
      #pragma unroll
      for (int mt=0;mt<4;++mt)
        #pragma unroll
        for (int nt=0;nt<4;++nt)
          acc[mt][nt] = __builtin_amdgcn_mfma_f32_16x16x32_bf16(af[mt], bf[nt], acc[mt][nt], 0,0,0);
    }
  }

  // y (+bias) into LDS fp32
  float bnv[4];
  #pragma unroll
  for (int nt=0;nt<4;++nt) bnv[nt] = bn[wn + nt*16 + lrow];
  __syncthreads();
  #pragma unroll
  for (int mt=0;mt<4;++mt)
    #pragma unroll
    for (int nt=0;nt<4;++nt)
      #pragma unroll
      for (int r=0;r<4;++r)
        yf[(wm+mt*16+quad*4+r)*132 + wn+nt*16+lrow] = acc[mt][nt][r] + bnv[nt];
  __syncthreads();

  // LayerNorm: 4 waves x 32 rows
  float g0 = lng[lane], g1 = lng[64+lane];
  float bb0 = lnb[lane], bb1 = lnb[64+lane];
  for (int rr = w*32; rr < w*32+32; ++rr){
    float v0 = yf[rr*132 + lane], v1 = yf[rr*132 + 64 + lane];
    float s = v0 + v1;
    #pragma unroll
    for (int off=32; off>0; off>>=1) s += __shfl_xor(s, off);
    float mu = s * (1.f/128.f);
    float d0 = v0-mu, d1 = v1-mu;
    float q = d0*d0 + d1*d1;
    #pragma unroll
    for (int off=32; off>0; off>>=1) q += __shfl_xor(q, off);
    float inv = rsqrtf(q*(1.f/128.f) + 1e-5f);
    int grow = m0 + rr;
    if (grow < NN){
      float o0 = d0*inv*g0 + bb0;
      float o1 = d1*inv*g1 + bb1;
      xb[(size_t)grow*128 + lane]      = f2bf(o0);
      xb[(size_t)grow*128 + 64 + lane] = f2bf(o1);
      if (writeOut){
        out[(size_t)grow*128 + lane]      = o0;
        out[(size_t)grow*128 + 64 + lane] = o1;
      }
    }
  }
}

extern "C" void kernel_launch(void* const* d_in, const int* in_sizes, int n_in,
                              void* d_out, int out_size, void* d_ws, size_t ws_size,
                              hipStream_t stream){
  const float* features = (const float*)d_in[0];
  const int*   src      = (const int*)d_in[1];
  const int*   dst      = (const int*)d_in[2];
  const float* W_fc     = (const float*)d_in[3];
  const float* attn_l   = (const float*)d_in[4];
  const float* attn_r   = (const float*)d_in[5];
  const float* W_res    = (const float*)d_in[6];
  const float* b_gat    = (const float*)d_in[7];
  const float* W_nrm    = (const float*)d_in[8];
  const float* b_nrm    = (const float*)d_in[9];
  const float* ln_g     = (const float*)d_in[10];
  const float* ln_b     = (const float*)d_in[11];
  float* out = (float*)d_out;

  // workspace (~122 MB)
  unsigned short* xb    = (unsigned short*)d_ws;            // [NPAD,128] bf16
  unsigned short* featH = xb + (size_t)NPAD*128;            // [NPAD,512] bf16
  unsigned short* hbuf  = featH + (size_t)NPAD*512;         // [NPAD,512] bf16
  unsigned short* W2t   = hbuf + (size_t)NPAD*512;          // [L,1024,128] bf16
  unsigned short* Wnt   = W2t + (size_t)LL*1024*128;        // [L,128,512] bf16
  float* el = (float*)(Wnt + (size_t)LL*128*512);           // [N,4]
  float* er = el + (size_t)NN*4;                            // [N,4]
  int* row_ptr = (int*)(er + (size_t)NN*4);                 // N+1
  int* cursor  = row_ptr + (NN+1);                          // N
  int* csr_src = cursor + NN;                               // E

  // prep: weights + x0 + CSR
  k_cvtw2<<<(LL*1024*128)/256, 256, 0, stream>>>(W_fc, W_res, W2t);
  k_cvtwn<<<(LL*128*512)/256, 256, 0, stream>>>(W_nrm, Wnt);
  k_cvtx<<<(NPAD*128)/256, 256, 0, stream>>>(features, xb);
  k_zero<<<(NN+255)/256, 256, 0, stream>>>(cursor, NN);
  k_hist<<<(EE+255)/256, 256, 0, stream>>>(dst, cursor);
  k_scan<<<1, 1024, 0, stream>>>(cursor, row_ptr);
  k_copy<<<(NN+255)/256, 256, 0, stream>>>(row_ptr, cursor, NN);
  k_fill<<<(EE+255)/256, 256, 0, stream>>>(src, dst, cursor, csr_src);

  for (int l=0; l<LL; ++l){
    const unsigned short* W2l = W2t + (size_t)l*1024*128;
    const unsigned short* Wnl = Wnt + (size_t)l*128*512;
    const float* al = attn_l + (size_t)l*HH*DD;
    const float* ar = attn_r + (size_t)l*HH*DD;
    const float* bg = b_gat  + (size_t)l*HDIM;
    const float* bn = b_nrm  + (size_t)l*DD;
    const float* lg = ln_g   + (size_t)l*DD;
    const float* lb = ln_b   + (size_t)l*DD;

    k_gemm1m<<<dim3(NPAD/128, 8), 256, 0, stream>>>(xb, W2l, featH, hbuf);
    k_attn2<<<NN/4, 256, 0, stream>>>(featH, al, ar, el, er);
    k_agg<<<NN/4, 256, 0, stream>>>(featH, hbuf, el, er, row_ptr, csr_src, bg);
    k_gemm3m<<<NPAD/128, 256, 0, stream>>>(hbuf, Wnl, bn, lg, lb, out, xb, (l==LL-1) ? 1 : 0);
  }
}